// Round 1
// baseline (354.301 us; speedup 1.0000x reference)
//
#include <hip/hip_runtime.h>
#include <cstdint>
#include <cstddef>

typedef _Float16 f16;
typedef f16 f16x2 __attribute__((ext_vector_type(2)));
typedef f16 f16x4 __attribute__((ext_vector_type(4)));
typedef f16 f16x8 __attribute__((ext_vector_type(8)));
typedef float f32x4 __attribute__((ext_vector_type(4)));

#define NEXP 8
#define BM 256
#define BN 256
#define BK 64

// async global->LDS, 16B per lane. LDS dest must be wave-uniform base + lane*16
// (staging index is tid*16 so this holds). Global source may be per-lane
// arbitrary (gathered rows / swizzled chunks are fine).
__device__ __forceinline__ void async_cp16(void* lds, const void* gsrc) {
  __builtin_amdgcn_global_load_lds(
      (const __attribute__((address_space(1))) void*)gsrc,
      (__attribute__((address_space(3))) void*)lds, 16, 0, 0);
}

// ---------------- K0: transpose gate weights gw[D,8] -> gwT[8,D] ----------------
__global__ __launch_bounds__(256) void k_gwT(const float* __restrict__ gw,
                                             float* __restrict__ gwT, int D) {
  int i = blockIdx.x * 256 + threadIdx.x;   // i < 8*D
  int e = i / D, d = i - e * D;
  gwT[i] = gw[d * NEXP + e];
}

// ---------------- K1: gating + x -> fp16 (single x pass, coalesced gwT) ------
// 256 threads = 4 waves, one token per wave. gwT (64KB) is L2-resident and
// every per-expert load is lane-contiguous (1 KB/wave-instr, 16 lines).
__global__ __launch_bounds__(256) void k_gate(
    const float* __restrict__ x, const float* __restrict__ gwT,
    f16* __restrict__ xb, int* __restrict__ gate, float* __restrict__ scale,
    int* __restrict__ cnt, float* __restrict__ probsum, int D)
{
  __shared__ float ps[NEXP];
  __shared__ int pc[NEXP];
  int tid = threadIdx.x, lane = tid & 63, w = tid >> 6;
  if (tid < NEXP) { ps[tid] = 0.f; pc[tid] = 0; }
  __syncthreads();

  int t = blockIdx.x * 4 + w;
  const float* xr = x + (size_t)t * D;
  f16* xbr = xb + (size_t)t * D;

  float acc[NEXP] = {};
  for (int d0 = lane * 4; d0 < D; d0 += 256) {
    float4 v = *(const float4*)(xr + d0);
    f16x4 h; h[0] = (f16)v.x; h[1] = (f16)v.y; h[2] = (f16)v.z; h[3] = (f16)v.w;
    *(f16x4*)(xbr + d0) = h;
#pragma unroll
    for (int e = 0; e < NEXP; e++) {
      float4 g = *(const float4*)(gwT + (size_t)e * D + d0);
      acc[e] += v.x * g.x + v.y * g.y + v.z * g.z + v.w * g.w;
    }
  }
#pragma unroll
  for (int e = 0; e < NEXP; e++) {
    float v = acc[e];
    for (int o = 32; o > 0; o >>= 1) v += __shfl_xor(v, o);
    acc[e] = v;
  }
  if (lane == 0) {
    float m = acc[0]; int g = 0;
#pragma unroll
    for (int e = 1; e < NEXP; e++) if (acc[e] > m) { m = acc[e]; g = e; }
    float pr[NEXP]; float ssum = 0.f;
#pragma unroll
    for (int e = 0; e < NEXP; e++) { pr[e] = __expf(acc[e] - m); ssum += pr[e]; }
    float inv = 1.0f / ssum;
#pragma unroll
    for (int e = 0; e < NEXP; e++) atomicAdd(&ps[e], pr[e] * inv);
    atomicAdd(&pc[g], 1);
    gate[t] = g;
    scale[t] = pr[g] * inv;
  }
  __syncthreads();
  if (tid < NEXP) {
    atomicAdd(&probsum[tid], ps[tid]);
    atomicAdd(&cnt[tid], pc[tid]);
  }
}

// ---------------- K2: build Wfull^T in fp16 ----------------
// wt[e][n][d] = sum_p rule[e,p,a,b] * W[e,p,i,j], d = a*Dp+i, n = b*Op+j.
// n-major, d contiguous. b looped in-block: W tile read once, used for all 4 b.
__global__ __launch_bounds__(256) void k_wfull(
    const float* __restrict__ Wp, const float* __restrict__ rule,
    f16* __restrict__ wt, int Dp, int Op, int D, int O)
{
  int bid = blockIdx.x;
  int it = Dp >> 5, jt = Op >> 5;
  int itile = bid % it; bid /= it;
  int jtile = bid % jt; bid /= jt;
  int e = bid;
  int i0 = itile * 32, j0 = jtile * 32;

  __shared__ float Wt[4][32][33];
  int tid = threadIdx.x;
  for (int idx = tid; idx < 4096; idx += 256) {
    int p = idx >> 10, rem = idx & 1023, ii = rem >> 5, jj = rem & 31;
    Wt[p][ii][jj] = Wp[(size_t)((e * 4 + p) * Dp + i0 + ii) * Op + j0 + jj];
  }
  __syncthreads();

  int ii = (tid & 15) * 2, jjb = tid >> 4;
#pragma unroll
  for (int b = 0; b < 4; b++) {
    float s[4][4];
#pragma unroll
    for (int p = 0; p < 4; p++)
#pragma unroll
      for (int a = 0; a < 4; a++)
        s[p][a] = rule[((e * 4 + p) * 4 + a) * 4 + b];
#pragma unroll
    for (int a = 0; a < 4; a++) {
#pragma unroll
      for (int jp = 0; jp < 2; jp++) {
        int jj = jjb + jp * 16;
        float v0 = 0.f, v1 = 0.f;
#pragma unroll
        for (int p = 0; p < 4; p++) {
          v0 += s[p][a] * Wt[p][ii][jj];
          v1 += s[p][a] * Wt[p][ii + 1][jj];
        }
        size_t n = (size_t)b * Op + j0 + jj;
        size_t dd = (size_t)a * Dp + i0 + ii;
        f16x2 hv; hv[0] = (f16)v0; hv[1] = (f16)v1;
        *(f16x2*)(wt + ((size_t)e * O + n) * D + dd) = hv;
      }
    }
  }
}

// ---------------- K3: plan (scan, loss, descriptors) ----------------
// Serial logic in LDS by thread 0 (16 global reads), then parallel writes
// (kills the ~80-deep serially-dependent global-write chain).
__global__ __launch_bounds__(128) void k_plan(
    const int* __restrict__ cnt, const float* __restrict__ probsum,
    int* __restrict__ offs, int* __restrict__ ndesc,
    int2* __restrict__ desc, float* __restrict__ otail, int T)
{
  __shared__ int soffs[NEXP + 1];
  __shared__ int snd;
  __shared__ float sloss;
  __shared__ int2 sdesc[96];
  int tid = threadIdx.x;
  if (tid == 0) {
    int off = 0, nd = 0; float loss = 0.f;
    for (int e = 0; e < NEXP; e++) {
      soffs[e] = off;
      int c = cnt[e];
      loss += probsum[e] * (float)c;
      for (int m0 = 0; m0 < c; m0 += BM) { sdesc[nd] = make_int2(e, m0); nd++; }
      off += c;
    }
    soffs[NEXP] = off;
    snd = nd;
    sloss = loss;
  }
  __syncthreads();
  if (tid <= NEXP) offs[tid] = soffs[tid];
  if (tid == 9) *ndesc = snd;
  if (tid == 10) {
    float invT = 1.0f / (float)T;
    otail[0] = (float)NEXP * sloss * invT * invT;  // balance loss
  }
  if (tid >= 16 && tid < 16 + NEXP) otail[1 + tid - 16] = (float)cnt[tid - 16];
  for (int i = tid; i < snd; i += 128) desc[i] = sdesc[i];
}

// ---------------- K4: scatter tokens by expert ----------------
__global__ __launch_bounds__(256) void k_scatter(
    const int* __restrict__ gate, const int* __restrict__ offs,
    int* __restrict__ cursor, int* __restrict__ perm)
{
  int t = blockIdx.x * 256 + threadIdx.x;
  int g = gate[t];
  int lane = threadIdx.x & 63;
  int pos = 0;
#pragma unroll
  for (int e = 0; e < NEXP; e++) {
    unsigned long long mask = __ballot(g == e);
    if (mask == 0ull) continue;            // wave-uniform
    int leader = __ffsll((unsigned long long)mask) - 1;
    int base = 0;
    if (lane == leader) base = atomicAdd(&cursor[e], (int)__popcll(mask));
    base = __shfl(base, leader);
    if (g == e) {
      int below = (int)__popcll(mask & ((1ull << lane) - 1ull));
      pos = offs[e] + base + below;
    }
  }
  perm[pos] = t;
}

// ---------------- K5: gathered top-1 GEMM, 256x256 phase-split schedule ------
// 8 waves (2M x 4N), per-wave output 128x64, BK=64, double-buffered LDS with
// prefetch distance 2 and COUNTED vmcnt (never 0 mid-loop). Each K-tile is
// split into 4 MFMA sub-phases (16 MFMA each); the ds_reads feeding sub-phase
// q+1 are issued before the MFMAs of sub-phase q, so LDS and MFMA pipes
// overlap instead of alternating (the 2-barrier lockstep that capped the old
// 128x128 kernel at MfmaUtil 24%). setprio(1) wraps each MFMA cluster.
// Swizzle: row of 64 f16 = 8 chunks of 16B; staging thread for (row, slot c)
// fetches global chunk gc = c ^ (row&7); readers index slot ck ^ (lr&7) ->
// max 2-way bank aliasing (free) on ds_read_b128, linear LDS dest for
// global_load_lds.
__global__ __launch_bounds__(512) void k_gemm(
    const f16* __restrict__ xb, const f16* __restrict__ wt,
    const float* __restrict__ bias, const int* __restrict__ perm,
    const int* __restrict__ cnt, const int* __restrict__ offs,
    const int* __restrict__ ndesc, const int2* __restrict__ desc,
    const float* __restrict__ scale, float* __restrict__ out, int D, int O)
{
  if ((int)blockIdx.y >= *ndesc) return;
  int2 dsc = desc[blockIdx.y];
  int e = dsc.x, m0 = dsc.y;
  int ce = cnt[e];
  int seg = offs[e];
  int n0 = blockIdx.x * BN;

  __shared__ f16 As[2][BM * BK];   // 2 x 32KB
  __shared__ f16 Bs[2][BN * BK];   // 2 x 32KB
  __shared__ int tokS[BM];
  __shared__ float scS[BM];

  int tid = threadIdx.x;
  if (tid < BM) {
    int idx = m0 + tid; if (idx > ce - 1) idx = ce - 1;  // clamp partial tile
    int tok = perm[seg + idx];
    tokS[tid] = tok;
    scS[tid] = scale[tok];
  }
  __syncthreads();

  // staging: 512 threads x 16B = 8KB/round; 4 rounds per 32KB tile.
  // round rr: row = (tid>>3) + rr*64, slot c = tid&7, global chunk c^(row&7).
  // 32-bit byte offsets (xb <= 32MB, wt <= 64MB) to keep VGPR pressure down.
  int sr = tid >> 3, sc = tid & 7;
  uint32_t offA[4], offB[4];
#pragma unroll
  for (int rr = 0; rr < 4; rr++) {
    int row = sr + rr * 64;
    int gc = sc ^ (row & 7);
    offA[rr] = ((uint32_t)tokS[row] * (uint32_t)D + (uint32_t)(gc * 8)) * 2u;
    offB[rr] = ((uint32_t)(e * O + n0 + row) * (uint32_t)D + (uint32_t)(gc * 8)) * 2u;
  }

#define STAGE(kk, pb)                                                         \
  do {                                                                        \
    _Pragma("unroll")                                                         \
    for (int rr = 0; rr < 4; rr++)                                            \
      async_cp16(&As[pb][rr * 4096 + tid * 8],                                \
                 (const char*)xb + offA[rr] + (kk) * (BK * 2));               \
    _Pragma("unroll")                                                         \
    for (int rr = 0; rr < 4; rr++)                                            \
      async_cp16(&Bs[pb][rr * 4096 + tid * 8],                                \
                 (const char*)wt + offB[rr] + (kk) * (BK * 2));               \
  } while (0)

  int lane = tid & 63;
  int wid = tid >> 6;
  int wr = wid >> 2, wc = wid & 3;          // wave tile: rows wr*128, cols wc*64
  int lr = lane & 15, q = lane >> 4;
  int aoff = (wr * 128 + lr) * BK;          // + mi*16*BK
  int boff = (wc * 64 + lr) * BK;           // + ni*16*BK
  int s0 = ((q ^ (lr & 7)) * 8);            // k-slice 0 swizzled slot
  int s1 = s0 ^ 32;                         // k-slice 1 (chunk ^ 4)

  f32x4 acc[8][4] = {};
  int nkt = D / BK;                          // 32

  STAGE(0, 0);
  STAGE(1, 1);
  asm volatile("s_waitcnt vmcnt(8)\n\ts_barrier" ::: "memory");  // buf0 ready

#pragma unroll 2
  for (int kt = 0; kt < nkt; ++kt) {
    int p = kt & 1;
    const f16* Ab = As[p];
    const f16* Bb = Bs[p];
    f16x8 a0[4], a1[4], a2[4], a3[4], b0[4], b1[4];

    // ---- sub-phase 0 frags (A rows 0..63 of wave, B, k-slice 0) ----
#pragma unroll
    for (int i = 0; i < 4; i++) {
      a0[i] = *(const f16x8*)&Ab[aoff + (i * 16) * BK + s0];
      b0[i] = *(const f16x8*)&Bb[boff + (i * 16) * BK + s0];
    }
    // issue sub-phase 1 reads before the MFMAs of sub-phase 0
#pragma unroll
    for (int i = 0; i < 4; i++)
      a1[i] = *(const f16x8*)&Ab[aoff + ((i + 4) * 16) * BK + s0];

    __builtin_amdgcn_s_setprio(1);
#pragma unroll
    for (int mi = 0; mi < 4; mi++)
#pragma unroll
      for (int ni = 0; ni < 4; ni++)
        acc[mi][ni] = __builtin_amdgcn_mfma_f32_16x16x32_f16(
            a0[mi], b0[ni], acc[mi][ni], 0, 0, 0);
    __builtin_amdgcn_s_setprio(0);

#pragma unroll
    for (int i = 0; i < 4; i++) {
      a2[i] = *(const f16x8*)&Ab[aoff + (i * 16) * BK + s1];
      b1[i] = *(const f16x8*)&Bb[boff + (i * 16) * BK + s1];
    }

    __builtin_amdgcn_s_setprio(1);
#pragma unroll
    for (int mi = 0; mi < 4; mi++)
#pragma unroll
      for (int ni = 0; ni < 4; ni++)
        acc[mi + 4][ni] = __builtin_amdgcn_mfma_f32_16x16x32_f16(
            a1[mi], b0[ni], acc[mi + 4][ni], 0, 0, 0);
    __builtin_amdgcn_s_setprio(0);

#pragma unroll
    for (int i = 0; i < 4; i++)
      a3[i] = *(const f16x8*)&Ab[aoff + ((i + 4) * 16) * BK + s1];

    __builtin_amdgcn_s_setprio(1);
#pragma unroll
    for (int mi = 0; mi < 4; mi++)
#pragma unroll
      for (int ni = 0; ni < 4; ni++)
        acc[mi][ni] = __builtin_amdgcn_mfma_f32_16x16x32_f16(
            a2[mi], b1[ni], acc[mi][ni], 0, 0, 0);
    __builtin_amdgcn_s_setprio(0);

    // all waves' ds_reads of buffer p done -> safe to restage it.
    // (lgkmcnt(0) also retires the a3/b1 reads above; their MFMAs follow.)
    asm volatile("s_waitcnt lgkmcnt(0)\n\ts_barrier" ::: "memory");
    if (kt + 2 < nkt) STAGE(kt + 2, p);

    __builtin_amdgcn_s_setprio(1);
#pragma unroll
    for (int mi = 0; mi < 4; mi++)
#pragma unroll
      for (int ni = 0; ni < 4; ni++)
        acc[mi + 4][ni] = __builtin_amdgcn_mfma_f32_16x16x32_f16(
            a3[mi], b1[ni], acc[mi + 4][ni], 0, 0, 0);
    __builtin_amdgcn_s_setprio(0);

    // buffer for kt+1 must be complete; the 8 loads for kt+2 stay in flight.
    if (kt + 2 < nkt)
      asm volatile("s_waitcnt vmcnt(8)\n\ts_barrier" ::: "memory");
    else if (kt + 1 < nkt)
      asm volatile("s_waitcnt vmcnt(0)\n\ts_barrier" ::: "memory");
  }
#undef STAGE

  // epilogue: C/D layout col=lane&15, row=(lane>>4)*4+reg
  float bv[4];
#pragma unroll
  for (int ni = 0; ni < 4; ni++)
    bv[ni] = bias[(size_t)e * O + n0 + wc * 64 + ni * 16 + lr];
#pragma unroll
  for (int mi = 0; mi < 8; mi++) {
#pragma unroll
    for (int rg = 0; rg < 4; rg++) {
      int rl = wr * 128 + mi * 16 + q * 4 + rg;
      if (m0 + rl < ce) {
        float s = scS[rl];
        float* orow = out + (size_t)tokS[rl] * O + n0 + wc * 64;
#pragma unroll
        for (int ni = 0; ni < 4; ni++)
          orow[ni * 16 + lr] = (acc[mi][ni][rg] + bv[ni]) * s;
      }
    }
  }
}

extern "C" void kernel_launch(void* const* d_in, const int* in_sizes, int n_in,
                              void* d_out, int out_size, void* d_ws, size_t ws_size,
                              hipStream_t stream)
{
  const float* x    = (const float*)d_in[0];   // [T, D]
  const float* gw   = (const float*)d_in[1];   // [D, 8]
  const float* rule = (const float*)d_in[2];   // [8, 4, 4, 4]
  const float* W    = (const float*)d_in[3];   // [8, 4, D/4, O/4]
  const float* bias = (const float*)d_in[4];   // [8, O]
  float* out = (float*)d_out;

  int D = in_sizes[1] / NEXP;
  int O = in_sizes[4] / NEXP;
  int T = in_sizes[0] / D;
  int Dp = D / 4, Op = O / 4;

  uint8_t* ws = (uint8_t*)d_ws;
  size_t off = 0;
  f16* xb = (f16*)(ws + off);  off += (size_t)T * D * 2;
  f16* wt = (f16*)(ws + off);  off += (size_t)NEXP * O * D * 2;
  int*   gate  = (int*)(ws + off);   off += (size_t)T * 4;
  float* scale = (float*)(ws + off); off += (size_t)T * 4;
  int*   perm  = (int*)(ws + off);   off += (size_t)T * 4;
  off = (off + 255) & ~(size_t)255;
  uint8_t* C = ws + off;
  int*   cnt     = (int*)(C + 0);
  float* probsum = (float*)(C + 32);
  int*   cursor  = (int*)(C + 64);
  int*   ndesc   = (int*)(C + 96);
  int*   offs    = (int*)(C + 128);
  int2*  desc    = (int2*)(C + 192);   // capacity to C+4096
  float* gwT     = (float*)(C + 4096); // [8, D] fp32

  // zero cnt/probsum/cursor/ndesc (ws is re-poisoned 0xAA before every call)
  hipMemsetAsync(C, 0, 128, stream);

  k_gwT<<<(NEXP * D) / 256, 256, 0, stream>>>(gw, gwT, D);
  k_gate<<<T / 4, 256, 0, stream>>>(x, gwT, xb, gate, scale, cnt, probsum, D);
  k_wfull<<<NEXP * (Op / 32) * (Dp / 32), 256, 0, stream>>>(W, rule, wt, Dp, Op, D, O);
  k_plan<<<1, 128, 0, stream>>>(cnt, probsum, offs, ndesc, desc, out + (size_t)T * O, T);
  k_scatter<<<T / 256, 256, 0, stream>>>(gate, offs, cursor, perm);

  int maxdesc = T / BM + NEXP;  // worst-case row-block descriptor count
  k_gemm<<<dim3(O / BN, maxdesc), 512, 0, stream>>>(
      xb, wt, bias, perm, cnt, offs, ndesc, desc, scale, out, D, O);
}